// Round 1
// baseline (1290.653 us; speedup 1.0000x reference)
//
#include <hip/hip_runtime.h>
#include <hip/hip_bf16.h>
#include <math.h>

#define N_NODES 50000
#define N_EDGES 800000
#define N_GRAPHS 128
#define ORIG_FEA 92
#define NBR_FEA 41
#define H 64
#define N_CONV 3
#define BN_EPS 1e-5f

__device__ __forceinline__ float sigmoidf_(float x) {
    return __fdividef(1.f, 1.f + __expf(-x));
}
__device__ __forceinline__ float softplusf_(float x) {
    return fmaxf(x, 0.f) + __logf(1.f + __expf(-fabsf(x)));
}

// ---------------------------------------------------------------------------
// Fold W_emb2 / b_emb2 / biases into per-layer edge-attr matrices:
//   W2f[a] = W_emb2 @ Wf[a][128:192]   [41 x 64]
//   cf[a]  = b_emb2 @ Wf[a][128:192] + bf[a]
// (same for the s-gate). 6 blocks: blockIdx = a*2 + gate.
// ---------------------------------------------------------------------------
__global__ __launch_bounds__(256) void fold_kernel(
    const float* __restrict__ W_emb2, const float* __restrict__ b_emb2,
    const float* __restrict__ Wf, const float* __restrict__ bf,
    const float* __restrict__ Ws, const float* __restrict__ bs,
    float* __restrict__ W2f, float* __restrict__ W2s,
    float* __restrict__ cf, float* __restrict__ cs) {
    int a = blockIdx.x >> 1, gate = blockIdx.x & 1;
    const float* W = (gate ? Ws : Wf) + a * 192 * H + 128 * H;  // [64][64]
    const float* bias = (gate ? bs : bf) + a * H;
    float* Wout = (gate ? W2s : W2f) + a * NBR_FEA * H;
    float* cout = (gate ? cs : cf) + a * H;
    for (int idx = threadIdx.x; idx < NBR_FEA * H; idx += blockDim.x) {
        int k = idx / H, j = idx % H;
        float acc = 0.f;
        for (int m = 0; m < H; ++m) acc += W_emb2[k * H + m] * W[m * H + j];
        Wout[idx] = acc;
    }
    for (int j = threadIdx.x; j < H; j += blockDim.x) {
        float acc = bias[j];
        for (int m = 0; m < H; ++m) acc += b_emb2[m] * W[m * H + j];
        cout[j] = acc;
    }
}

// ---------------------------------------------------------------------------
// h = x @ W_emb1 + b_emb1     (50000 x 92 -> 64), one wave per node (strided)
// ---------------------------------------------------------------------------
__global__ __launch_bounds__(256) void embed_kernel(
    const float* __restrict__ x, const float* __restrict__ W,
    const float* __restrict__ b, float* __restrict__ h) {
    __shared__ float lw[ORIG_FEA * H];  // 23.5 KB
    for (int i = threadIdx.x; i < ORIG_FEA * H; i += blockDim.x) lw[i] = W[i];
    __syncthreads();
    int lane = threadIdx.x & 63;
    int wid = (blockIdx.x * blockDim.x + threadIdx.x) >> 6;
    int nw = (gridDim.x * blockDim.x) >> 6;
    for (int n = wid; n < N_NODES; n += nw) {
        int nu = __builtin_amdgcn_readfirstlane(n);
        const float* xr = x + (size_t)nu * ORIG_FEA;  // uniform base -> scalar loads
        float acc = b[lane];
#pragma unroll
        for (int k = 0; k < ORIG_FEA; ++k) acc += xr[k] * lw[k * H + lane];
        h[(size_t)nu * H + lane] = acc;
    }
}

// ---------------------------------------------------------------------------
// Per-node projections for one conv layer:
//   Pf = h@Wf_i, Qf = h@Wf_j, Ps = h@Ws_i, Qs = h@Ws_j; also hsum = h (residual)
// ---------------------------------------------------------------------------
__global__ __launch_bounds__(256) void node_proj_kernel(
    const float* __restrict__ h,
    const float* __restrict__ Wf, const float* __restrict__ Ws,
    float* __restrict__ Pf, float* __restrict__ Qf,
    float* __restrict__ Ps, float* __restrict__ Qs,
    float* __restrict__ hsum) {
    __shared__ float lw[4 * H * H];  // 64 KB: [Wf_i, Wf_j, Ws_i, Ws_j]
    for (int i = threadIdx.x; i < H * H; i += blockDim.x) {
        lw[i] = Wf[i];
        lw[H * H + i] = Wf[H * H + i];
        lw[2 * H * H + i] = Ws[i];
        lw[3 * H * H + i] = Ws[H * H + i];
    }
    __syncthreads();
    int lane = threadIdx.x & 63;
    int wid = (blockIdx.x * blockDim.x + threadIdx.x) >> 6;
    int nw = (gridDim.x * blockDim.x) >> 6;
    for (int n = wid; n < N_NODES; n += nw) {
        int nu = __builtin_amdgcn_readfirstlane(n);
        const float* hr = h + (size_t)nu * H;  // uniform base
        float pf = 0.f, qf = 0.f, ps = 0.f, qs = 0.f;
#pragma unroll
        for (int k = 0; k < H; ++k) {
            float s = hr[k];
            pf += s * lw[k * H + lane];
            qf += s * lw[H * H + k * H + lane];
            ps += s * lw[2 * H * H + k * H + lane];
            qs += s * lw[3 * H * H + k * H + lane];
        }
        size_t o = (size_t)nu * H + lane;
        Pf[o] = pf; Qf[o] = qf; Ps[o] = ps; Qs[o] = qs;
        hsum[o] = hr[lane];  // residual init for segment-sum
    }
}

// ---------------------------------------------------------------------------
// Edge kernel: msg = sigmoid(Pf[dst]+Qf[src]+ea@W2f+cf) *
//                    softplus(Ps[dst]+Qs[src]+ea@W2s+cs); atomic add to hsum[dst]
// One wave per edge (grid-strided). W2f/W2s columns cached in VGPRs per lane.
// ---------------------------------------------------------------------------
__global__ __launch_bounds__(256) void edge_kernel(
    const int* __restrict__ ei, const float* __restrict__ ea,
    const float* __restrict__ Pf, const float* __restrict__ Qf,
    const float* __restrict__ Ps, const float* __restrict__ Qs,
    const float* __restrict__ W2f, const float* __restrict__ W2s,
    const float* __restrict__ cf, const float* __restrict__ cs,
    float* __restrict__ hsum) {
    int lane = threadIdx.x & 63;
    float wf[NBR_FEA], ws2[NBR_FEA];
#pragma unroll
    for (int k = 0; k < NBR_FEA; ++k) {
        wf[k] = W2f[k * H + lane];
        ws2[k] = W2s[k * H + lane];
    }
    float cfl = cf[lane], csl = cs[lane];
    int wid = (blockIdx.x * blockDim.x + threadIdx.x) >> 6;
    int nw = (gridDim.x * blockDim.x) >> 6;
    for (int e = wid; e < N_EDGES; e += nw) {
        int eu = __builtin_amdgcn_readfirstlane(e);
        int src = ei[eu];             // edge_index[0] = source (x_j)
        int dst = ei[N_EDGES + eu];   // edge_index[1] = target (x_i, agg index)
        float af = cfl + Pf[(size_t)dst * H + lane] + Qf[(size_t)src * H + lane];
        float as = csl + Ps[(size_t)dst * H + lane] + Qs[(size_t)src * H + lane];
        const float* er = ea + (size_t)eu * NBR_FEA;  // uniform base -> scalar loads
#pragma unroll
        for (int k = 0; k < NBR_FEA; ++k) {
            float s = er[k];
            af += s * wf[k];
            as += s * ws2[k];
        }
        atomicAdd(&hsum[(size_t)dst * H + lane], sigmoidf_(af) * softplusf_(as));
    }
}

// ---------------------------------------------------------------------------
// BatchNorm statistics: per-feature sum and sum-of-squares over all nodes
// ---------------------------------------------------------------------------
__global__ __launch_bounds__(256) void bn_stats_kernel(
    const float* __restrict__ hsum, float* __restrict__ stats) {
    int lane = threadIdx.x & 63;
    int wl = threadIdx.x >> 6;
    int wid = (blockIdx.x * blockDim.x + threadIdx.x) >> 6;
    int nw = (gridDim.x * blockDim.x) >> 6;
    float s = 0.f, s2 = 0.f;
    for (int n = wid; n < N_NODES; n += nw) {
        float v = hsum[(size_t)n * H + lane];
        s += v;
        s2 += v * v;
    }
    __shared__ float ls[4 * 2 * H];
    ls[wl * 2 * H + lane] = s;
    ls[wl * 2 * H + H + lane] = s2;
    __syncthreads();
    if (wl == 0) {
        float a = ls[lane] + ls[2 * H + lane] + ls[4 * H + lane] + ls[6 * H + lane];
        float b = ls[H + lane] + ls[3 * H + lane] + ls[5 * H + lane] + ls[7 * H + lane];
        atomicAdd(&stats[lane], a);
        atomicAdd(&stats[H + lane], b);
    }
}

// ---------------------------------------------------------------------------
// BatchNorm apply (+ optional ReLU): h = (hsum - mu) * rsqrt(var+eps)*gamma + beta
// ---------------------------------------------------------------------------
__global__ __launch_bounds__(256) void bn_apply_kernel(
    const float* __restrict__ hsum, const float* __restrict__ stats,
    const float* __restrict__ gamma, const float* __restrict__ beta,
    float* __restrict__ h, int relu) {
    int idx0 = blockIdx.x * blockDim.x + threadIdx.x;
    int stride = gridDim.x * blockDim.x;
    const float inv_n = 1.f / (float)N_NODES;
    for (int idx = idx0; idx < N_NODES * H; idx += stride) {
        int j = idx & (H - 1);
        float mu = stats[j] * inv_n;
        float var = stats[H + j] * inv_n - mu * mu;
        float inv = rsqrtf(var + BN_EPS);
        float v = (hsum[idx] - mu) * inv * gamma[j] + beta[j];
        if (relu) v = fmaxf(v, 0.f);
        h[idx] = v;
    }
}

// ---------------------------------------------------------------------------
// Mean-pool per graph (accumulate), then tiny MLP head
// ---------------------------------------------------------------------------
__global__ __launch_bounds__(256) void pool_kernel(
    const float* __restrict__ h, const int* __restrict__ batch,
    float* __restrict__ gsum, float* __restrict__ gcnt) {
    int lane = threadIdx.x & 63;
    int wid = (blockIdx.x * blockDim.x + threadIdx.x) >> 6;
    int nw = (gridDim.x * blockDim.x) >> 6;
    for (int n = wid; n < N_NODES; n += nw) {
        int nu = __builtin_amdgcn_readfirstlane(n);
        int g = batch[nu];
        atomicAdd(&gsum[(size_t)g * H + lane], h[(size_t)nu * H + lane]);
        if (lane == 0) atomicAdd(&gcnt[g], 1.f);
    }
}

__global__ __launch_bounds__(64) void mlp_kernel(
    const float* __restrict__ gsum, const float* __restrict__ gcnt,
    const float* __restrict__ W1, const float* __restrict__ b1,
    const float* __restrict__ W2, const float* __restrict__ b2,
    const float* __restrict__ Wo, const float* __restrict__ bo,
    float* __restrict__ out) {
    int g = blockIdx.x;
    int lane = threadIdx.x;
    __shared__ float y[H];
    float cnt = fmaxf(gcnt[g], 1.f);
    y[lane] = gsum[(size_t)g * H + lane] / cnt;
    __syncthreads();
    float acc = b1[lane];
#pragma unroll
    for (int k = 0; k < H; ++k) acc += y[k] * W1[k * H + lane];
    float y1 = softplusf_(acc);
    __syncthreads();
    y[lane] = y1;
    __syncthreads();
    acc = b2[lane];
#pragma unroll
    for (int k = 0; k < H; ++k) acc += y[k] * W2[k * H + lane];
    float y2 = softplusf_(acc);
    float t = y2 * Wo[lane];
#pragma unroll
    for (int o = 32; o > 0; o >>= 1) t += __shfl_down(t, o, 64);
    if (lane == 0) out[g] = t + bo[0];
}

extern "C" void kernel_launch(void* const* d_in, const int* in_sizes, int n_in,
                              void* d_out, int out_size, void* d_ws, size_t ws_size,
                              hipStream_t stream) {
    const float* x = (const float*)d_in[0];
    const float* ea = (const float*)d_in[1];
    const int* ei = (const int*)d_in[2];
    const int* batch = (const int*)d_in[3];
    const float* W_emb1 = (const float*)d_in[4];
    const float* b_emb1 = (const float*)d_in[5];
    const float* W_emb2 = (const float*)d_in[6];
    const float* b_emb2 = (const float*)d_in[7];
    const float* Wf = (const float*)d_in[8];
    const float* bf = (const float*)d_in[9];
    const float* Ws = (const float*)d_in[10];
    const float* bs = (const float*)d_in[11];
    const float* gamma = (const float*)d_in[12];
    const float* beta = (const float*)d_in[13];
    const float* W1 = (const float*)d_in[14];
    const float* b1 = (const float*)d_in[15];
    const float* W2 = (const float*)d_in[16];
    const float* b2 = (const float*)d_in[17];
    const float* Wo = (const float*)d_in[18];
    const float* bo = (const float*)d_in[19];
    float* out = (float*)d_out;

    float* w = (float*)d_ws;
    float* stats = w;                       // 3*128
    float* gsum = w + 3 * 2 * H;            // 128*64
    float* gcnt = gsum + N_GRAPHS * H;      // 128
    float* h = gcnt + N_GRAPHS;             // 3.2M
    float* hsum = h + (size_t)N_NODES * H;
    float* Pf = hsum + (size_t)N_NODES * H;
    float* Qf = Pf + (size_t)N_NODES * H;
    float* Ps = Qf + (size_t)N_NODES * H;
    float* Qs = Ps + (size_t)N_NODES * H;
    float* W2f = Qs + (size_t)N_NODES * H;  // 3*41*64
    float* W2s = W2f + 3 * NBR_FEA * H;
    float* cf = W2s + 3 * NBR_FEA * H;      // 3*64
    float* cs = cf + 3 * H;

    // zero the atomic accumulator regions (stats + gsum + gcnt are contiguous)
    hipMemsetAsync(w, 0, (3 * 2 * H + N_GRAPHS * H + N_GRAPHS) * sizeof(float), stream);

    fold_kernel<<<6, 256, 0, stream>>>(W_emb2, b_emb2, Wf, bf, Ws, bs, W2f, W2s, cf, cs);
    embed_kernel<<<512, 256, 0, stream>>>(x, W_emb1, b_emb1, h);

    for (int a = 0; a < N_CONV; ++a) {
        node_proj_kernel<<<512, 256, 0, stream>>>(h, Wf + a * 192 * H, Ws + a * 192 * H,
                                                  Pf, Qf, Ps, Qs, hsum);
        edge_kernel<<<1024, 256, 0, stream>>>(ei, ea, Pf, Qf, Ps, Qs,
                                              W2f + a * NBR_FEA * H, W2s + a * NBR_FEA * H,
                                              cf + a * H, cs + a * H, hsum);
        bn_stats_kernel<<<256, 256, 0, stream>>>(hsum, stats + a * 2 * H);
        bn_apply_kernel<<<2048, 256, 0, stream>>>(hsum, stats + a * 2 * H,
                                                  gamma + a * H, beta + a * H, h,
                                                  a != N_CONV - 1 ? 1 : 0);
    }

    pool_kernel<<<784, 256, 0, stream>>>(h, batch, gsum, gcnt);
    mlp_kernel<<<128, 64, 0, stream>>>(gsum, gcnt, W1, b1, W2, b2, Wo, bo, out);
}

// Round 2
// 1232.788 us; speedup vs baseline: 1.0469x; 1.0469x over previous
//
#include <hip/hip_runtime.h>
#include <hip/hip_bf16.h>
#include <math.h>

#define N_NODES 50000
#define N_EDGES 800000
#define N_GRAPHS 128
#define ORIG_FEA 92
#define NBR_FEA 41
#define H 64
#define N_CONV 3
#define BN_EPS 1e-5f

typedef float v2f __attribute__((ext_vector_type(2)));

__device__ __forceinline__ float sigmoidf_(float x) {
    return __fdividef(1.f, 1.f + __expf(-x));
}
__device__ __forceinline__ float softplusf_(float x) {
    return fmaxf(x, 0.f) + __logf(1.f + __expf(-fabsf(x)));
}

// ---------------------------------------------------------------------------
// Fold W_emb2 / b_emb2 / biases into per-layer edge-attr matrices, stored
// gate-interleaved: W2c[a][k][2*j+gate] (gate 0 = f, 1 = s), cfs[a][2*j+gate].
//   W2{f,s}[a] = W_emb2 @ W{f,s}[a][128:192]
//   c{f,s}[a]  = b_emb2 @ W{f,s}[a][128:192] + b{f,s}[a]
// 6 blocks: blockIdx = a*2 + gate.
// ---------------------------------------------------------------------------
__global__ __launch_bounds__(256) void fold_kernel(
    const float* __restrict__ W_emb2, const float* __restrict__ b_emb2,
    const float* __restrict__ Wf, const float* __restrict__ bf,
    const float* __restrict__ Ws, const float* __restrict__ bs,
    float* __restrict__ W2c, float* __restrict__ cfs) {
    int a = blockIdx.x >> 1, gate = blockIdx.x & 1;
    const float* W = (gate ? Ws : Wf) + a * 192 * H + 128 * H;  // [64][64]
    const float* bias = (gate ? bs : bf) + a * H;
    float* Wout = W2c + a * NBR_FEA * 2 * H;
    float* cout = cfs + a * 2 * H;
    for (int idx = threadIdx.x; idx < NBR_FEA * H; idx += blockDim.x) {
        int k = idx / H, j = idx % H;
        float acc = 0.f;
        for (int m = 0; m < H; ++m) acc += W_emb2[k * H + m] * W[m * H + j];
        Wout[k * 2 * H + 2 * j + gate] = acc;
    }
    for (int j = threadIdx.x; j < H; j += blockDim.x) {
        float acc = bias[j];
        for (int m = 0; m < H; ++m) acc += b_emb2[m] * W[m * H + j];
        cout[2 * j + gate] = acc;
    }
}

// ---------------------------------------------------------------------------
// h = x @ W_emb1 + b_emb1     (50000 x 92 -> 64), one wave per node (strided)
// ---------------------------------------------------------------------------
__global__ __launch_bounds__(256) void embed_kernel(
    const float* __restrict__ x, const float* __restrict__ W,
    const float* __restrict__ b, float* __restrict__ h) {
    __shared__ float lw[ORIG_FEA * H];  // 23.5 KB
    for (int i = threadIdx.x; i < ORIG_FEA * H; i += blockDim.x) lw[i] = W[i];
    __syncthreads();
    int lane = threadIdx.x & 63;
    int wid = (blockIdx.x * blockDim.x + threadIdx.x) >> 6;
    int nw = (gridDim.x * blockDim.x) >> 6;
    for (int n = wid; n < N_NODES; n += nw) {
        int nu = __builtin_amdgcn_readfirstlane(n);
        const float* xr = x + (size_t)nu * ORIG_FEA;  // uniform base -> scalar loads
        float acc = b[lane];
#pragma unroll
        for (int k = 0; k < ORIG_FEA; ++k) acc += xr[k] * lw[k * H + lane];
        h[(size_t)nu * H + lane] = acc;
    }
}

// ---------------------------------------------------------------------------
// Per-node projections for one conv layer, written gate-interleaved:
//   NPi[n][2*j+0] = (h@Wf_i)[n][j]   NPi[n][2*j+1] = (h@Ws_i)[n][j]
//   NPj[n][2*j+0] = (h@Wf_j)[n][j]   NPj[n][2*j+1] = (h@Ws_j)[n][j]
// Also hsum = h (residual init for the edge aggregation).
// ---------------------------------------------------------------------------
__global__ __launch_bounds__(256) void node_proj_kernel(
    const float* __restrict__ h,
    const float* __restrict__ Wf, const float* __restrict__ Ws,
    float* __restrict__ NPi, float* __restrict__ NPj,
    float* __restrict__ hsum) {
    __shared__ float lw[4 * H * H];  // 64 KB: [Wf_i, Wf_j, Ws_i, Ws_j]
    for (int i = threadIdx.x; i < H * H; i += blockDim.x) {
        lw[i] = Wf[i];
        lw[H * H + i] = Wf[H * H + i];
        lw[2 * H * H + i] = Ws[i];
        lw[3 * H * H + i] = Ws[H * H + i];
    }
    __syncthreads();
    int lane = threadIdx.x & 63;
    int wid = (blockIdx.x * blockDim.x + threadIdx.x) >> 6;
    int nw = (gridDim.x * blockDim.x) >> 6;
    for (int n = wid; n < N_NODES; n += nw) {
        int nu = __builtin_amdgcn_readfirstlane(n);
        const float* hr = h + (size_t)nu * H;  // uniform base
        float pf = 0.f, qf = 0.f, ps = 0.f, qs = 0.f;
#pragma unroll
        for (int k = 0; k < H; ++k) {
            float s = hr[k];
            pf += s * lw[k * H + lane];
            qf += s * lw[H * H + k * H + lane];
            ps += s * lw[2 * H * H + k * H + lane];
            qs += s * lw[3 * H * H + k * H + lane];
        }
        v2f pi; pi.x = pf; pi.y = ps;
        v2f pj; pj.x = qf; pj.y = qs;
        *(v2f*)&NPi[(size_t)nu * 2 * H + 2 * lane] = pi;
        *(v2f*)&NPj[(size_t)nu * 2 * H + 2 * lane] = pj;
        hsum[(size_t)nu * H + lane] = hr[lane];  // residual init
    }
}

// ---------------------------------------------------------------------------
// Edge kernel, packed-fp32: lane l holds feature l of BOTH gates as float2.
//   acc = cfs + NPi[dst] + NPj[src] + sum_k ea[k] * W2c[k]    (v_pk_fma_f32)
//   msg = sigmoid(acc.x) * softplus(acc.y); atomicAdd to hsum[dst][l]
// W2 pairs pinned in VGPRs (asm keep-alive prevents rematerialization).
// ---------------------------------------------------------------------------
__global__ __launch_bounds__(256, 2) void edge_kernel(
    const int* __restrict__ ei, const float* __restrict__ ea,
    const float* __restrict__ NPi, const float* __restrict__ NPj,
    const float* __restrict__ W2c, const float* __restrict__ cfs,
    float* __restrict__ hsum) {
    int lane = threadIdx.x & 63;
    v2f w[NBR_FEA];
#pragma unroll
    for (int k = 0; k < NBR_FEA; ++k)
        w[k] = *(const v2f*)&W2c[k * 2 * H + 2 * lane];
    v2f c2 = *(const v2f*)&cfs[2 * lane];
#pragma unroll
    for (int k = 0; k < NBR_FEA; ++k) asm volatile("" : "+v"(w[k]));  // pin in VGPRs
    int wid = (blockIdx.x * blockDim.x + threadIdx.x) >> 6;
    int nw = (gridDim.x * blockDim.x) >> 6;
    for (int e = wid; e < N_EDGES; e += nw) {
        int eu = __builtin_amdgcn_readfirstlane(e);
        int src = ei[eu];             // edge_index[0] = source (x_j)
        int dst = ei[N_EDGES + eu];   // edge_index[1] = target (x_i, agg index)
        v2f pi = *(const v2f*)&NPi[(size_t)dst * 2 * H + 2 * lane];
        v2f pj = *(const v2f*)&NPj[(size_t)src * 2 * H + 2 * lane];
        v2f acc = c2 + pi + pj;
        const float* er = ea + (size_t)eu * NBR_FEA;  // uniform base -> scalar loads
#pragma unroll
        for (int k = 0; k < NBR_FEA; ++k) acc += w[k] * er[k];
        float msg = sigmoidf_(acc.x) * softplusf_(acc.y);
        atomicAdd(&hsum[(size_t)dst * H + lane], msg);
    }
}

// ---------------------------------------------------------------------------
// BatchNorm statistics: per-feature sum and sum-of-squares over all nodes
// ---------------------------------------------------------------------------
__global__ __launch_bounds__(256) void bn_stats_kernel(
    const float* __restrict__ hsum, float* __restrict__ stats) {
    int lane = threadIdx.x & 63;
    int wl = threadIdx.x >> 6;
    int wid = (blockIdx.x * blockDim.x + threadIdx.x) >> 6;
    int nw = (gridDim.x * blockDim.x) >> 6;
    float s = 0.f, s2 = 0.f;
    for (int n = wid; n < N_NODES; n += nw) {
        float v = hsum[(size_t)n * H + lane];
        s += v;
        s2 += v * v;
    }
    __shared__ float ls[4 * 2 * H];
    ls[wl * 2 * H + lane] = s;
    ls[wl * 2 * H + H + lane] = s2;
    __syncthreads();
    if (wl == 0) {
        float a = ls[lane] + ls[2 * H + lane] + ls[4 * H + lane] + ls[6 * H + lane];
        float b = ls[H + lane] + ls[3 * H + lane] + ls[5 * H + lane] + ls[7 * H + lane];
        atomicAdd(&stats[lane], a);
        atomicAdd(&stats[H + lane], b);
    }
}

// ---------------------------------------------------------------------------
// BatchNorm apply (+ optional ReLU): h = (hsum - mu) * rsqrt(var+eps)*gamma + beta
// ---------------------------------------------------------------------------
__global__ __launch_bounds__(256) void bn_apply_kernel(
    const float* __restrict__ hsum, const float* __restrict__ stats,
    const float* __restrict__ gamma, const float* __restrict__ beta,
    float* __restrict__ h, int relu) {
    int idx0 = blockIdx.x * blockDim.x + threadIdx.x;
    int stride = gridDim.x * blockDim.x;
    const float inv_n = 1.f / (float)N_NODES;
    for (int idx = idx0; idx < N_NODES * H; idx += stride) {
        int j = idx & (H - 1);
        float mu = stats[j] * inv_n;
        float var = stats[H + j] * inv_n - mu * mu;
        float inv = rsqrtf(var + BN_EPS);
        float v = (hsum[idx] - mu) * inv * gamma[j] + beta[j];
        if (relu) v = fmaxf(v, 0.f);
        h[idx] = v;
    }
}

// ---------------------------------------------------------------------------
// Mean-pool per graph (accumulate), then tiny MLP head
// ---------------------------------------------------------------------------
__global__ __launch_bounds__(256) void pool_kernel(
    const float* __restrict__ h, const int* __restrict__ batch,
    float* __restrict__ gsum, float* __restrict__ gcnt) {
    int lane = threadIdx.x & 63;
    int wid = (blockIdx.x * blockDim.x + threadIdx.x) >> 6;
    int nw = (gridDim.x * blockDim.x) >> 6;
    for (int n = wid; n < N_NODES; n += nw) {
        int nu = __builtin_amdgcn_readfirstlane(n);
        int g = batch[nu];
        atomicAdd(&gsum[(size_t)g * H + lane], h[(size_t)nu * H + lane]);
        if (lane == 0) atomicAdd(&gcnt[g], 1.f);
    }
}

__global__ __launch_bounds__(64) void mlp_kernel(
    const float* __restrict__ gsum, const float* __restrict__ gcnt,
    const float* __restrict__ W1, const float* __restrict__ b1,
    const float* __restrict__ W2, const float* __restrict__ b2,
    const float* __restrict__ Wo, const float* __restrict__ bo,
    float* __restrict__ out) {
    int g = blockIdx.x;
    int lane = threadIdx.x;
    __shared__ float y[H];
    float cnt = fmaxf(gcnt[g], 1.f);
    y[lane] = gsum[(size_t)g * H + lane] / cnt;
    __syncthreads();
    float acc = b1[lane];
#pragma unroll
    for (int k = 0; k < H; ++k) acc += y[k] * W1[k * H + lane];
    float y1 = softplusf_(acc);
    __syncthreads();
    y[lane] = y1;
    __syncthreads();
    acc = b2[lane];
#pragma unroll
    for (int k = 0; k < H; ++k) acc += y[k] * W2[k * H + lane];
    float y2 = softplusf_(acc);
    float t = y2 * Wo[lane];
#pragma unroll
    for (int o = 32; o > 0; o >>= 1) t += __shfl_down(t, o, 64);
    if (lane == 0) out[g] = t + bo[0];
}

extern "C" void kernel_launch(void* const* d_in, const int* in_sizes, int n_in,
                              void* d_out, int out_size, void* d_ws, size_t ws_size,
                              hipStream_t stream) {
    const float* x = (const float*)d_in[0];
    const float* ea = (const float*)d_in[1];
    const int* ei = (const int*)d_in[2];
    const int* batch = (const int*)d_in[3];
    const float* W_emb1 = (const float*)d_in[4];
    const float* b_emb1 = (const float*)d_in[5];
    const float* W_emb2 = (const float*)d_in[6];
    const float* b_emb2 = (const float*)d_in[7];
    const float* Wf = (const float*)d_in[8];
    const float* bf = (const float*)d_in[9];
    const float* Ws = (const float*)d_in[10];
    const float* bs = (const float*)d_in[11];
    const float* gamma = (const float*)d_in[12];
    const float* beta = (const float*)d_in[13];
    const float* W1 = (const float*)d_in[14];
    const float* b1 = (const float*)d_in[15];
    const float* W2 = (const float*)d_in[16];
    const float* b2 = (const float*)d_in[17];
    const float* Wo = (const float*)d_in[18];
    const float* bo = (const float*)d_in[19];
    float* out = (float*)d_out;

    float* w = (float*)d_ws;
    float* stats = w;                        // 3*128
    float* gsum = w + 3 * 2 * H;             // 128*64
    float* gcnt = gsum + N_GRAPHS * H;       // 128
    float* h = gcnt + N_GRAPHS;              // 3.2M
    float* hsum = h + (size_t)N_NODES * H;   // 3.2M
    float* NPi = hsum + (size_t)N_NODES * H; // 6.4M
    float* NPj = NPi + (size_t)N_NODES * 2 * H; // 6.4M
    float* W2c = NPj + (size_t)N_NODES * 2 * H; // 3*41*128
    float* cfs = W2c + 3 * NBR_FEA * 2 * H;     // 3*128

    // zero the atomic accumulator regions (stats + gsum + gcnt are contiguous)
    hipMemsetAsync(w, 0, (3 * 2 * H + N_GRAPHS * H + N_GRAPHS) * sizeof(float), stream);

    fold_kernel<<<6, 256, 0, stream>>>(W_emb2, b_emb2, Wf, bf, Ws, bs, W2c, cfs);
    embed_kernel<<<512, 256, 0, stream>>>(x, W_emb1, b_emb1, h);

    for (int a = 0; a < N_CONV; ++a) {
        node_proj_kernel<<<512, 256, 0, stream>>>(h, Wf + a * 192 * H, Ws + a * 192 * H,
                                                  NPi, NPj, hsum);
        edge_kernel<<<2048, 256, 0, stream>>>(ei, ea, NPi, NPj,
                                              W2c + a * NBR_FEA * 2 * H,
                                              cfs + a * 2 * H, hsum);
        bn_stats_kernel<<<256, 256, 0, stream>>>(hsum, stats + a * 2 * H);
        bn_apply_kernel<<<2048, 256, 0, stream>>>(hsum, stats + a * 2 * H,
                                                  gamma + a * H, beta + a * H, h,
                                                  a != N_CONV - 1 ? 1 : 0);
    }

    pool_kernel<<<784, 256, 0, stream>>>(h, batch, gsum, gcnt);
    mlp_kernel<<<128, 64, 0, stream>>>(gsum, gcnt, W1, b1, W2, b2, Wo, bo, out);
}